// Round 1
// baseline (540.374 us; speedup 1.0000x reference)
//
#include <hip/hip_runtime.h>
#include <hip/hip_bf16.h>
#include <cstdint>

// Problem: B=32, S=2048, H=1024
//   c[b,o]   = hidden[b,:].Wh[o,:] + bias[o]        (Wh = W_attn[:, :H])
//   e[b,s,o] = enc[b,s,:].We[o,:]                   (We = W_attn[:, H:])
//   logit[b,s] = sum_o tanh(e + c) * v[o];  out = softmax over s
//
// R3: single fused GEMM kernel, no 128 MB enc-bf16 intermediate.
//  - 1024 blocks x 512 threads, BM=64 rows/block, K pipelined in 8 phases of 128
//    through a 2x16KB double-buffered, XOR-swizzled bf16 LDS slab (one barrier/phase).
//  - B pre-packed fragment-major (convert_W2) so B-frags are coalesced 1KB global
//    loads from L2 (Wbf2 = 2 MB, L2-resident) -- no LDS, no barrier for B.
//  - per-wave partial logits -> softmax sums 8 slices (deterministic, no atomics).

#define HDIM 1024
#define SDIM 2048
#define MTOT 65536

typedef __attribute__((ext_vector_type(8))) short short8;   // 8 bf16
typedef __attribute__((ext_vector_type(4))) float floatx4;  // MFMA acc

__device__ __forceinline__ unsigned short f2bf(float f) {
    unsigned int u = __float_as_uint(f);
    u += 0x7fffu + ((u >> 16) & 1u);   // RNE
    return (unsigned short)(u >> 16);
}
__device__ __forceinline__ unsigned int pack2(float a, float b) {
    return (unsigned int)f2bf(a) | ((unsigned int)f2bf(b) << 16);
}
__device__ __forceinline__ float fast_tanh(float x) {
    float e2 = __expf(2.f * x);
    return 1.f - 2.f * __builtin_amdgcn_rcpf(e2 + 1.f);
}

// ---- convert We (W_attn[:, H:2H], row stride 2H) into fragment-major bf16 ----
// tile (jt in [0,64), kc in [0,32)): 16 n-rows x 32 k; ushort base = (jt*32+kc)*512.
// lane l = g*16+lc holds B[n=jt*16+lc][k=kc*32+g*8+jj], jj in [0,8) at base+l*8+jj.
__global__ __launch_bounds__(256) void convert_W2(const float* __restrict__ W,
                                                  unsigned short* __restrict__ Wbf2) {
    int T = blockIdx.x * 256 + threadIdx.x;   // [0, 131072): (n, k8)
    int n  = T >> 7;
    int k8 = T & 127;
    int k  = k8 * 8;
    const float4* src = (const float4*)(W + (size_t)n * 2048 + 1024 + k);
    float4 f0 = src[0], f1 = src[1];
    int jt = n >> 4, lc = n & 15, kc = k8 >> 2, g = k8 & 3;
    uint4 u;
    u.x = pack2(f0.x, f0.y); u.y = pack2(f0.z, f0.w);
    u.z = pack2(f1.x, f1.y); u.w = pack2(f1.z, f1.w);
    *(uint4*)(Wbf2 + (size_t)(jt * 32 + kc) * 512 + (g * 16 + lc) * 8) = u;
}

// ---- c[b,o] = hidden[b,:].Wh[o,:] + bias[o]; one block per o ----
__global__ __launch_bounds__(256) void calc_c(const float* __restrict__ hid,
                                              const float* __restrict__ W,
                                              const float* __restrict__ bias,
                                              float* __restrict__ c) {
    __shared__ float red[4][32];
    const int o = blockIdx.x;
    const int wave = threadIdx.x >> 6, lane = threadIdx.x & 63;
    const int k = wave * 256 + lane * 4;
    const float4 wv = *(const float4*)(W + (size_t)o * 2048 + k);
    float acc[32];
#pragma unroll
    for (int b = 0; b < 32; ++b) {
        const float4 h = *(const float4*)(hid + b * HDIM + k);
        acc[b] = wv.x * h.x + wv.y * h.y + wv.z * h.z + wv.w * h.w;
    }
#pragma unroll
    for (int b = 0; b < 32; ++b) {
        float x = acc[b];
        for (int off = 32; off; off >>= 1) x += __shfl_xor(x, off);
        if (lane == 0) red[wave][b] = x;
    }
    __syncthreads();
    if (threadIdx.x < 32) {
        int b = threadIdx.x;
        c[b * HDIM + o] = red[0][b] + red[1][b] + red[2][b] + red[3][b] + bias[o];
    }
}

// ---- fused GEMM + tanh + v-dot ----
#define PHN 8     // K phases
#define PHK 128   // K per phase

__global__ __launch_bounds__(512, 2) void attn_fused(const float* __restrict__ enc,
                                                     const unsigned short* __restrict__ Wbf2,
                                                     const float* __restrict__ c,
                                                     const float* __restrict__ v,
                                                     float* __restrict__ part) {
    // slab: 64 rows x 128 k bf16, row stride 128 ushorts; 16B chunk c16 of row r
    // stored at slot (c16 ^ (r&7)) -> frag reads are 2-way (free) bank aliasing.
    __shared__ __align__(16) unsigned short slab[2][64 * 128];   // 2 x 16 KB

    const int tid  = threadIdx.x;
    const int lane = tid & 63;
    const int wave = tid >> 6;    // 0..7
    const int grp  = lane >> 4;   // 0..3
    const int lc   = lane & 15;

    const int m0 = blockIdx.x * 64;
    const int b  = m0 >> 11;      // batch (64-row blocks never straddle b)

    // staging geometry: wave covers rows [wave*8, wave*8+8); q in [0,4):
    //   row = wave*8 + q*2 + (lane>>5),  kk = (lane&31)*4  (floats within 128-window)
    const int s_kk   = (lane & 31) * 4;
    const int s_rsub = lane >> 5;
    const int s_c16  = (lane & 31) >> 1;   // 16B chunk index of this lane's 4 floats
    const int s_b8   = lane & 1;           // low/high 8B of that chunk

    floatx4 acc[2][4][4];
#pragma unroll
    for (int cg = 0; cg < 2; ++cg)
#pragma unroll
        for (int i = 0; i < 4; ++i)
#pragma unroll
            for (int j = 0; j < 4; ++j) acc[cg][i][j] = (floatx4){0.f, 0.f, 0.f, 0.f};

    const short8* Bfr = (const short8*)Wbf2;   // tile*64 + lane indexing (16B units)

    float4 ld[4];
    // prologue: stage phase 0 into buf 0
#pragma unroll
    for (int q = 0; q < 4; ++q) {
        int row = wave * 8 + q * 2 + s_rsub;
        ld[q] = *(const float4*)(enc + (size_t)(m0 + row) * HDIM + s_kk);
    }
#pragma unroll
    for (int q = 0; q < 4; ++q) {
        int row  = wave * 8 + q * 2 + s_rsub;
        int slot = s_c16 ^ (row & 7);
        uint2 u = {pack2(ld[q].x, ld[q].y), pack2(ld[q].z, ld[q].w)};
        *(uint2*)(&slab[0][row * 128 + slot * 8 + s_b8 * 4]) = u;
    }

    // B lookahead ring: bf holds frags for flat step s (cg = s>>2, kc = s&3)
    short8 bf[4], bn[4];
#pragma unroll
    for (int j = 0; j < 4; ++j)
        bf[j] = Bfr[(size_t)((wave * 8 + 0 * 4 + j) * 32 + 0) * 64 + lane];

#pragma unroll 1
    for (int p = 0; p < PHN; ++p) {
        __syncthreads();   // slab[p&1] fully written

        if (p < PHN - 1) {
#pragma unroll
            for (int q = 0; q < 4; ++q) {
                int row = wave * 8 + q * 2 + s_rsub;
                ld[q] = *(const float4*)(enc + (size_t)(m0 + row) * HDIM +
                                         (p + 1) * PHK + s_kk);
            }
        }

        const unsigned short* sl = slab[p & 1];
#pragma unroll
        for (int s = 0; s < 8; ++s) {                 // cg = s>>2, kc = s&3
            const int cg = s >> 2, kc = s & 3;
            short8 af[4];
#pragma unroll
            for (int i = 0; i < 4; ++i) {
                int row  = i * 16 + lc;
                int slot = (kc * 4 + grp) ^ (lc & 7);
                af[i] = *(const short8*)(sl + row * 128 + slot * 16 / 2);
            }
            // prefetch B for step s+1 (crosses into next phase at s==7)
            {
                const int cg2 = (s < 7) ? ((s + 1) >> 2) : 0;
                const int kc2 = (s < 7) ? ((s + 1) & 3) : 0;
                const int pn  = (s < 7) ? p : ((p < PHN - 1) ? p + 1 : p);
#pragma unroll
                for (int j = 0; j < 4; ++j)
                    bn[j] = Bfr[(size_t)((wave * 8 + cg2 * 4 + j) * 32 +
                                         pn * 4 + kc2) * 64 + lane];
            }
#pragma unroll
            for (int i = 0; i < 4; ++i)
#pragma unroll
                for (int j = 0; j < 4; ++j)
                    acc[cg][i][j] = __builtin_amdgcn_mfma_f32_16x16x32_bf16(
                        af[i], bf[j], acc[cg][i][j], 0, 0, 0);
#pragma unroll
            for (int j = 0; j < 4; ++j) bf[j] = bn[j];
        }

        if (p < PHN - 1) {
#pragma unroll
            for (int q = 0; q < 4; ++q) {
                int row  = wave * 8 + q * 2 + s_rsub;
                int slot = s_c16 ^ (row & 7);
                uint2 u = {pack2(ld[q].x, ld[q].y), pack2(ld[q].z, ld[q].w)};
                *(uint2*)(&slab[(p + 1) & 1][row * 128 + slot * 8 + s_b8 * 4]) = u;
            }
        }
    }

    // epilogue: rowsum over this wave's 128 cols, tanh(e + c) * v
    float rowsum[4][4];
#pragma unroll
    for (int i = 0; i < 4; ++i)
#pragma unroll
        for (int r = 0; r < 4; ++r) rowsum[i][r] = 0.f;

#pragma unroll
    for (int cg = 0; cg < 2; ++cg)
#pragma unroll
        for (int j = 0; j < 4; ++j) {
            const int n  = wave * 128 + cg * 64 + j * 16 + lc;
            const float vn = v[n];
            const float cv = c[b * HDIM + n];
#pragma unroll
            for (int i = 0; i < 4; ++i)
#pragma unroll
                for (int r = 0; r < 4; ++r)
                    rowsum[i][r] = fmaf(fast_tanh(acc[cg][i][j][r] + cv), vn,
                                        rowsum[i][r]);
        }

#pragma unroll
    for (int i = 0; i < 4; ++i)
#pragma unroll
        for (int r = 0; r < 4; ++r) {
            float x = rowsum[i][r];
            x += __shfl_xor(x, 8);
            x += __shfl_xor(x, 4);
            x += __shfl_xor(x, 2);
            x += __shfl_xor(x, 1);
            if (lc == 0)
                part[(size_t)wave * MTOT + m0 + i * 16 + grp * 4 + r] = x;
        }
}

// ---- softmax over S=2048 per batch, summing npart partial logit slices ----
__global__ __launch_bounds__(256) void softmax_k(const float* __restrict__ partials,
                                                 float* __restrict__ out, int npart) {
    __shared__ float wred[4];
    const int bb = blockIdx.x;
    const int tid = threadIdx.x;
    const int wave = tid >> 6, lane = tid & 63;

    float vals[8];
    float lmax = -INFINITY;
#pragma unroll
    for (int q = 0; q < 8; ++q) {
        const size_t idx = (size_t)bb * SDIM + q * 256 + tid;
        float x = 0.f;
        for (int p = 0; p < npart; ++p) x += partials[(size_t)p * MTOT + idx];
        vals[q] = x;
        lmax = fmaxf(lmax, x);
    }
    for (int off = 32; off; off >>= 1) lmax = fmaxf(lmax, __shfl_xor(lmax, off));
    if (lane == 0) wred[wave] = lmax;
    __syncthreads();
    lmax = fmaxf(fmaxf(wred[0], wred[1]), fmaxf(wred[2], wred[3]));
    __syncthreads();

    float e[8];
    float s = 0.f;
#pragma unroll
    for (int q = 0; q < 8; ++q) {
        e[q] = __expf(vals[q] - lmax);
        s += e[q];
    }
    for (int off = 32; off; off >>= 1) s += __shfl_xor(s, off);
    if (lane == 0) wred[wave] = s;
    __syncthreads();
    s = wred[0] + wred[1] + wred[2] + wred[3];
    const float inv = 1.f / s;
#pragma unroll
    for (int q = 0; q < 8; ++q)
        out[(size_t)bb * SDIM + q * 256 + tid] = e[q] * inv;
}

extern "C" void kernel_launch(void* const* d_in, const int* in_sizes, int n_in,
                              void* d_out, int out_size, void* d_ws, size_t ws_size,
                              hipStream_t stream) {
    const float* hidden = (const float*)d_in[0];   // (1, 32, 1024)
    const float* enc    = (const float*)d_in[1];   // (32, 2048, 1024)
    const float* W      = (const float*)d_in[2];   // (1024, 2048)
    const float* battn  = (const float*)d_in[3];   // (1024,)
    const float* v      = (const float*)d_in[4];   // (1024,)
    float* out = (float*)d_out;                    // (32, 2048)

    char* ws = (char*)d_ws;
    float* c             = (float*)ws;                          // 128 KB
    float* part          = (float*)(ws + (128 << 10));          // 8*65536*4 = 2 MB
    unsigned short* Wbf2 = (unsigned short*)(ws + (128 << 10) + (2 << 20));  // 2 MB

    hipLaunchKernelGGL(convert_W2, dim3(512),  dim3(256), 0, stream, W, Wbf2);
    hipLaunchKernelGGL(calc_c,     dim3(1024), dim3(256), 0, stream, hidden, W, battn, c);
    hipLaunchKernelGGL(attn_fused, dim3(1024), dim3(512), 0, stream, enc, Wbf2, c, v, part);
    hipLaunchKernelGGL(softmax_k,  dim3(32),   dim3(256), 0, stream, part, out, 8);
}

// Round 2
// 521.669 us; speedup vs baseline: 1.0359x; 1.0359x over previous
//
#include <hip/hip_runtime.h>
#include <hip/hip_bf16.h>
#include <cstdint>

// Problem: B=32, S=2048, H=1024
//   c[b,o]   = hidden[b,:].Wh[o,:] + bias[o]        (Wh = W_attn[:, :H])
//   e[b,s,o] = enc[b,s,:].We[o,:]                   (We = W_attn[:, H:])
//   logit[b,s] = sum_o tanh(e + c) * v[o];  out = softmax over s
//
// R4: (a) staging pack/ds_write interleaved into MFMA steps 4..7 (no serial
//     phase tail), (b) s_setprio around MFMA clusters, (c) in-block LDS
//     reduction of the 8 per-wave partial logits -> logits written once
//     (no 2MB part slab), (d) convert_W2 + calc_c merged into one launch.

#define HDIM 1024
#define SDIM 2048
#define MTOT 65536

typedef __attribute__((ext_vector_type(8))) short short8;   // 8 bf16
typedef __attribute__((ext_vector_type(4))) float floatx4;  // MFMA acc

__device__ __forceinline__ unsigned short f2bf(float f) {
    unsigned int u = __float_as_uint(f);
    u += 0x7fffu + ((u >> 16) & 1u);   // RNE
    return (unsigned short)(u >> 16);
}
__device__ __forceinline__ unsigned int pack2(float a, float b) {
    return (unsigned int)f2bf(a) | ((unsigned int)f2bf(b) << 16);
}
__device__ __forceinline__ float fast_tanh(float x) {
    float e2 = __expf(2.f * x);
    return 1.f - 2.f * __builtin_amdgcn_rcpf(e2 + 1.f);
}

// ---- merged prep kernel ----
// blocks [0,512):   convert We (W_attn[:, H:2H]) into fragment-major bf16 Wbf2
// blocks [512,1536): c[b,o] = hidden[b,:].Wh[o,:] + bias[o], one block per o
__global__ __launch_bounds__(256) void prep(const float* __restrict__ W,
                                            unsigned short* __restrict__ Wbf2,
                                            const float* __restrict__ hid,
                                            const float* __restrict__ bias,
                                            float* __restrict__ c) {
    __shared__ float red[4][32];
    if (blockIdx.x < 512) {
        // convert_W2 body
        int T = blockIdx.x * 256 + threadIdx.x;   // [0, 131072): (n, k8)
        int n  = T >> 7;
        int k8 = T & 127;
        int k  = k8 * 8;
        const float4* src = (const float4*)(W + (size_t)n * 2048 + 1024 + k);
        float4 f0 = src[0], f1 = src[1];
        int jt = n >> 4, lc = n & 15, kc = k8 >> 2, g = k8 & 3;
        uint4 u;
        u.x = pack2(f0.x, f0.y); u.y = pack2(f0.z, f0.w);
        u.z = pack2(f1.x, f1.y); u.w = pack2(f1.z, f1.w);
        *(uint4*)(Wbf2 + (size_t)(jt * 32 + kc) * 512 + (g * 16 + lc) * 8) = u;
    } else {
        // calc_c body
        const int o = blockIdx.x - 512;
        const int wave = threadIdx.x >> 6, lane = threadIdx.x & 63;
        const int k = wave * 256 + lane * 4;
        const float4 wv = *(const float4*)(W + (size_t)o * 2048 + k);
        float acc[32];
#pragma unroll
        for (int b = 0; b < 32; ++b) {
            const float4 h = *(const float4*)(hid + b * HDIM + k);
            acc[b] = wv.x * h.x + wv.y * h.y + wv.z * h.z + wv.w * h.w;
        }
#pragma unroll
        for (int b = 0; b < 32; ++b) {
            float x = acc[b];
            for (int off = 32; off; off >>= 1) x += __shfl_xor(x, off);
            if (lane == 0) red[wave][b] = x;
        }
        __syncthreads();
        if (threadIdx.x < 32) {
            int b = threadIdx.x;
            c[b * HDIM + o] = red[0][b] + red[1][b] + red[2][b] + red[3][b] + bias[o];
        }
    }
}

// ---- fused GEMM + tanh + v-dot ----
#define PHN 8     // K phases
#define PHK 128   // K per phase

__global__ __launch_bounds__(512, 2) void attn_fused(const float* __restrict__ enc,
                                                     const unsigned short* __restrict__ Wbf2,
                                                     const float* __restrict__ c,
                                                     const float* __restrict__ v,
                                                     float* __restrict__ logits) {
    // slab: 64 rows x 128 k bf16, row stride 128 ushorts; 16B chunk c16 of row r
    // stored at slot (c16 ^ (r&7)).
    __shared__ __align__(16) unsigned short slab[2][64 * 128];   // 2 x 16 KB

    const int tid  = threadIdx.x;
    const int lane = tid & 63;
    const int wave = tid >> 6;    // 0..7
    const int grp  = lane >> 4;   // 0..3
    const int lc   = lane & 15;

    const int m0 = blockIdx.x * 64;
    const int b  = m0 >> 11;      // batch (64-row blocks never straddle b)

    const int s_kk   = (lane & 31) * 4;
    const int s_rsub = lane >> 5;
    const int s_c16  = (lane & 31) >> 1;
    const int s_b8   = lane & 1;

    floatx4 acc[2][4][4];
#pragma unroll
    for (int cg = 0; cg < 2; ++cg)
#pragma unroll
        for (int i = 0; i < 4; ++i)
#pragma unroll
            for (int j = 0; j < 4; ++j) acc[cg][i][j] = (floatx4){0.f, 0.f, 0.f, 0.f};

    const short8* Bfr = (const short8*)Wbf2;

    float4 ld[4];
    // prologue: stage phase 0 into buf 0
#pragma unroll
    for (int q = 0; q < 4; ++q) {
        int row = wave * 8 + q * 2 + s_rsub;
        ld[q] = *(const float4*)(enc + (size_t)(m0 + row) * HDIM + s_kk);
    }
#pragma unroll
    for (int q = 0; q < 4; ++q) {
        int row  = wave * 8 + q * 2 + s_rsub;
        int slot = s_c16 ^ (row & 7);
        uint2 u = {pack2(ld[q].x, ld[q].y), pack2(ld[q].z, ld[q].w)};
        *(uint2*)(&slab[0][row * 128 + slot * 8 + s_b8 * 4]) = u;
    }

    // B lookahead ring
    short8 bf[4], bn[4];
#pragma unroll
    for (int j = 0; j < 4; ++j)
        bf[j] = Bfr[(size_t)((wave * 8 + 0 * 4 + j) * 32 + 0) * 64 + lane];

#pragma unroll 1
    for (int p = 0; p < PHN; ++p) {
        __syncthreads();   // slab[p&1] fully written

        if (p < PHN - 1) {
#pragma unroll
            for (int q = 0; q < 4; ++q) {
                int row = wave * 8 + q * 2 + s_rsub;
                ld[q] = *(const float4*)(enc + (size_t)(m0 + row) * HDIM +
                                         (p + 1) * PHK + s_kk);
            }
        }

        const unsigned short* sl = slab[p & 1];
#pragma unroll
        for (int s = 0; s < 8; ++s) {                 // cg = s>>2, kc = s&3
            const int cg = s >> 2, kc = s & 3;
            short8 af[4];
#pragma unroll
            for (int i = 0; i < 4; ++i) {
                int row  = i * 16 + lc;
                int slot = (kc * 4 + grp) ^ (lc & 7);
                af[i] = *(const short8*)(sl + row * 128 + slot * 16 / 2);
            }
            // prefetch B for step s+1 (crosses into next phase at s==7)
            {
                const int cg2 = (s < 7) ? ((s + 1) >> 2) : 0;
                const int kc2 = (s < 7) ? ((s + 1) & 3) : 0;
                const int pn  = (s < 7) ? p : ((p < PHN - 1) ? p + 1 : p);
#pragma unroll
                for (int j = 0; j < 4; ++j)
                    bn[j] = Bfr[(size_t)((wave * 8 + cg2 * 4 + j) * 32 +
                                         pn * 4 + kc2) * 64 + lane];
            }
            __builtin_amdgcn_s_setprio(1);
#pragma unroll
            for (int i = 0; i < 4; ++i)
#pragma unroll
                for (int j = 0; j < 4; ++j)
                    acc[cg][i][j] = __builtin_amdgcn_mfma_f32_16x16x32_bf16(
                        af[i], bf[j], acc[cg][i][j], 0, 0, 0);
            __builtin_amdgcn_s_setprio(0);
            // staging pack + LDS write for next phase, spread over steps 4..7
            // (slab[(p+1)&1] was last read in phase p-1; safe after this
            //  phase's top barrier)
            if (p < PHN - 1 && s >= 4) {
                const int q = s - 4;
                int row  = wave * 8 + q * 2 + s_rsub;
                int slot = s_c16 ^ (row & 7);
                uint2 u = {pack2(ld[q].x, ld[q].y), pack2(ld[q].z, ld[q].w)};
                *(uint2*)(&slab[(p + 1) & 1][row * 128 + slot * 8 + s_b8 * 4]) = u;
            }
#pragma unroll
            for (int j = 0; j < 4; ++j) bf[j] = bn[j];
        }
    }

    // epilogue: rowsum over this wave's 128 cols, tanh(e + c) * v
    float rowsum[4][4];
#pragma unroll
    for (int i = 0; i < 4; ++i)
#pragma unroll
        for (int r = 0; r < 4; ++r) rowsum[i][r] = 0.f;

#pragma unroll
    for (int cg = 0; cg < 2; ++cg)
#pragma unroll
        for (int j = 0; j < 4; ++j) {
            const int n  = wave * 128 + cg * 64 + j * 16 + lc;
            const float vn = v[n];
            const float cv = c[b * HDIM + n];
#pragma unroll
            for (int i = 0; i < 4; ++i)
#pragma unroll
                for (int r = 0; r < 4; ++r)
                    rowsum[i][r] = fmaf(fast_tanh(acc[cg][i][j][r] + cv), vn,
                                        rowsum[i][r]);
        }

    // in-block reduction across the 8 waves (each wave owns all 64 rows
    // for a disjoint 128-col slice). red overlays slab[0] (2 KB), which no
    // wave reads after the phase-7 top barrier.
    float* red = (float*)slab;
#pragma unroll
    for (int i = 0; i < 4; ++i)
#pragma unroll
        for (int r = 0; r < 4; ++r) {
            float x = rowsum[i][r];
            x += __shfl_xor(x, 8);
            x += __shfl_xor(x, 4);
            x += __shfl_xor(x, 2);
            x += __shfl_xor(x, 1);
            if (lc == 0) red[wave * 64 + i * 16 + grp * 4 + r] = x;
        }
    __syncthreads();
    if (tid < 64) {
        float ssum = 0.f;
#pragma unroll
        for (int w = 0; w < 8; ++w) ssum += red[w * 64 + tid];
        logits[m0 + tid] = ssum;
    }
}

// ---- softmax over S=2048 per batch ----
__global__ __launch_bounds__(256) void softmax_k(const float* __restrict__ logits,
                                                 float* __restrict__ out) {
    __shared__ float wred[4];
    const int bb = blockIdx.x;
    const int tid = threadIdx.x;
    const int wave = tid >> 6, lane = tid & 63;

    float vals[8];
    float lmax = -INFINITY;
#pragma unroll
    for (int q = 0; q < 8; ++q) {
        vals[q] = logits[(size_t)bb * SDIM + q * 256 + tid];
        lmax = fmaxf(lmax, vals[q]);
    }
    for (int off = 32; off; off >>= 1) lmax = fmaxf(lmax, __shfl_xor(lmax, off));
    if (lane == 0) wred[wave] = lmax;
    __syncthreads();
    lmax = fmaxf(fmaxf(wred[0], wred[1]), fmaxf(wred[2], wred[3]));
    __syncthreads();

    float e[8];
    float s = 0.f;
#pragma unroll
    for (int q = 0; q < 8; ++q) {
        e[q] = __expf(vals[q] - lmax);
        s += e[q];
    }
    for (int off = 32; off; off >>= 1) s += __shfl_xor(s, off);
    if (lane == 0) wred[wave] = s;
    __syncthreads();
    s = wred[0] + wred[1] + wred[2] + wred[3];
    const float inv = 1.f / s;
#pragma unroll
    for (int q = 0; q < 8; ++q)
        out[(size_t)bb * SDIM + q * 256 + tid] = e[q] * inv;
}

extern "C" void kernel_launch(void* const* d_in, const int* in_sizes, int n_in,
                              void* d_out, int out_size, void* d_ws, size_t ws_size,
                              hipStream_t stream) {
    const float* hidden = (const float*)d_in[0];   // (1, 32, 1024)
    const float* enc    = (const float*)d_in[1];   // (32, 2048, 1024)
    const float* W      = (const float*)d_in[2];   // (1024, 2048)
    const float* battn  = (const float*)d_in[3];   // (1024,)
    const float* v      = (const float*)d_in[4];   // (1024,)
    float* out = (float*)d_out;                    // (32, 2048)

    char* ws = (char*)d_ws;
    float* c             = (float*)ws;                           // 128 KB
    float* logits        = (float*)(ws + (128 << 10));           // 256 KB
    unsigned short* Wbf2 = (unsigned short*)(ws + (384 << 10));  // 2 MB

    hipLaunchKernelGGL(prep,       dim3(1536), dim3(256), 0, stream, W, Wbf2, hidden, battn, c);
    hipLaunchKernelGGL(attn_fused, dim3(1024), dim3(512), 0, stream, enc, Wbf2, c, v, logits);
    hipLaunchKernelGGL(softmax_k,  dim3(32),   dim3(256), 0, stream, logits, out);
}

// Round 3
// 491.928 us; speedup vs baseline: 1.0985x; 1.0605x over previous
//
#include <hip/hip_runtime.h>
#include <hip/hip_bf16.h>
#include <cstdint>

// Problem: B=32, S=2048, H=1024
//   c[b,o]   = hidden[b,:].Wh[o,:] + bias[o]        (Wh = W_attn[:, :H])
//   e[b,s,o] = enc[b,s,:].We[o,:]                   (We = W_attn[:, H:])
//   logit[b,s] = sum_o tanh(e + c) * v[o];  out = softmax over s
//
// R5: retile BM=128 x BN=512 (grid 512 strips x 2 N-halves), 8 waves split
//     1M x 8N: wave = 128 rows x 64 cols -> 32 MFMA per 4 B-frag loads
//     (2x compute per L2 load vs R4), B L2 traffic 2GB -> 1GB.
//     acc unchanged at 128 regs. Staging back at phase tail (R2's interleave
//     raised bank conflicts), no setprio (m190). 2-slice part reduction.

#define HDIM 1024
#define SDIM 2048
#define MTOT 65536

typedef __attribute__((ext_vector_type(8))) short short8;   // 8 bf16
typedef __attribute__((ext_vector_type(4))) float floatx4;  // MFMA acc

__device__ __forceinline__ unsigned short f2bf(float f) {
    unsigned int u = __float_as_uint(f);
    u += 0x7fffu + ((u >> 16) & 1u);   // RNE
    return (unsigned short)(u >> 16);
}
__device__ __forceinline__ unsigned int pack2(float a, float b) {
    return (unsigned int)f2bf(a) | ((unsigned int)f2bf(b) << 16);
}
__device__ __forceinline__ float fast_tanh(float x) {
    float e2 = __expf(2.f * x);
    return 1.f - 2.f * __builtin_amdgcn_rcpf(e2 + 1.f);
}

// ---- merged prep kernel ----
// blocks [0,512):   convert We (W_attn[:, H:2H]) into fragment-major bf16 Wbf2
// blocks [512,1536): c[b,o] = hidden[b,:].Wh[o,:] + bias[o], one block per o
__global__ __launch_bounds__(256) void prep(const float* __restrict__ W,
                                            unsigned short* __restrict__ Wbf2,
                                            const float* __restrict__ hid,
                                            const float* __restrict__ bias,
                                            float* __restrict__ c) {
    __shared__ float red[4][32];
    if (blockIdx.x < 512) {
        int T = blockIdx.x * 256 + threadIdx.x;   // [0, 131072): (n, k8)
        int n  = T >> 7;
        int k8 = T & 127;
        int k  = k8 * 8;
        const float4* src = (const float4*)(W + (size_t)n * 2048 + 1024 + k);
        float4 f0 = src[0], f1 = src[1];
        int jt = n >> 4, lc = n & 15, kc = k8 >> 2, g = k8 & 3;
        uint4 u;
        u.x = pack2(f0.x, f0.y); u.y = pack2(f0.z, f0.w);
        u.z = pack2(f1.x, f1.y); u.w = pack2(f1.z, f1.w);
        *(uint4*)(Wbf2 + (size_t)(jt * 32 + kc) * 512 + (g * 16 + lc) * 8) = u;
    } else {
        const int o = blockIdx.x - 512;
        const int wave = threadIdx.x >> 6, lane = threadIdx.x & 63;
        const int k = wave * 256 + lane * 4;
        const float4 wv = *(const float4*)(W + (size_t)o * 2048 + k);
        float acc[32];
#pragma unroll
        for (int b = 0; b < 32; ++b) {
            const float4 h = *(const float4*)(hid + b * HDIM + k);
            acc[b] = wv.x * h.x + wv.y * h.y + wv.z * h.z + wv.w * h.w;
        }
#pragma unroll
        for (int b = 0; b < 32; ++b) {
            float x = acc[b];
            for (int off = 32; off; off >>= 1) x += __shfl_xor(x, off);
            if (lane == 0) red[wave][b] = x;
        }
        __syncthreads();
        if (threadIdx.x < 32) {
            int b = threadIdx.x;
            c[b * HDIM + o] = red[0][b] + red[1][b] + red[2][b] + red[3][b] + bias[o];
        }
    }
}

// ---- fused GEMM + tanh + v-dot ----
#define PHN 8     // K phases
#define PHK 128   // K per phase

__global__ __launch_bounds__(512, 2) void attn_fused(const float* __restrict__ enc,
                                                     const unsigned short* __restrict__ Wbf2,
                                                     const float* __restrict__ c,
                                                     const float* __restrict__ v,
                                                     float* __restrict__ part) {
    // slab: 128 rows x 128 k bf16, row stride 128 ushorts (256B); 16B chunk c16
    // of row r stored at slot (c16 ^ (r&7)).
    __shared__ __align__(16) unsigned short slab[2][128 * 128];   // 2 x 32 KB

    const int tid  = threadIdx.x;
    const int lane = tid & 63;
    const int wave = tid >> 6;    // 0..7
    const int grp  = lane >> 4;   // 0..3
    const int lc   = lane & 15;

    const int strip = blockIdx.x >> 1;        // 0..511
    const int nhalf = blockIdx.x & 1;         // which 512-col half
    const int m0 = strip * 128;
    const int b  = m0 >> 11;      // batch (128-row strips never straddle b)
    const int cb = nhalf * 512 + wave * 64;   // wave's global col base

    // staging geometry: wave covers rows [wave*16, wave*16+16); q in [0,8):
    //   row = wave*16 + q*2 + (lane>>5),  kk = (lane&31)*4
    const int s_kk   = (lane & 31) * 4;
    const int s_rsub = lane >> 5;
    const int s_c16  = (lane & 31) >> 1;
    const int s_b8   = lane & 1;

    floatx4 acc[8][4];
#pragma unroll
    for (int i = 0; i < 8; ++i)
#pragma unroll
        for (int j = 0; j < 4; ++j) acc[i][j] = (floatx4){0.f, 0.f, 0.f, 0.f};

    const short8* Bfr = (const short8*)Wbf2;
    const int jt0 = nhalf * 32 + wave * 4;    // wave's first 16-col B tile

    float4 ld[8];
    // prologue: stage phase 0 into buf 0
#pragma unroll
    for (int q = 0; q < 8; ++q) {
        int row = wave * 16 + q * 2 + s_rsub;
        ld[q] = *(const float4*)(enc + (size_t)(m0 + row) * HDIM + s_kk);
    }
#pragma unroll
    for (int q = 0; q < 8; ++q) {
        int row  = wave * 16 + q * 2 + s_rsub;
        int slot = s_c16 ^ (row & 7);
        uint2 u = {pack2(ld[q].x, ld[q].y), pack2(ld[q].z, ld[q].w)};
        *(uint2*)(&slab[0][row * 128 + slot * 8 + s_b8 * 4]) = u;
    }

    // B lookahead ring: bf holds frags for current K-32 step
    short8 bf[4], bn[4];
#pragma unroll
    for (int j = 0; j < 4; ++j)
        bf[j] = Bfr[(size_t)((jt0 + j) * 32 + 0) * 64 + lane];

#pragma unroll 1
    for (int p = 0; p < PHN; ++p) {
        __syncthreads();   // slab[p&1] fully written

        if (p < PHN - 1) {
#pragma unroll
            for (int q = 0; q < 8; ++q) {
                int row = wave * 16 + q * 2 + s_rsub;
                ld[q] = *(const float4*)(enc + (size_t)(m0 + row) * HDIM +
                                         (p + 1) * PHK + s_kk);
            }
        }

        const unsigned short* sl = slab[p & 1];
#pragma unroll
        for (int s = 0; s < 4; ++s) {                 // kc = s (K-32 sub-step)
            const int kc = s;
            short8 af[8];
#pragma unroll
            for (int i = 0; i < 8; ++i) {
                int row  = i * 16 + lc;
                int slot = (kc * 4 + grp) ^ (lc & 7);
                af[i] = *(const short8*)(sl + row * 128 + slot * 8);
            }
            // prefetch B for step s+1 (crosses into next phase at s==3)
            {
                const int kc2 = (s + 1) & 3;
                const int pn  = (s < 3) ? p : ((p < PHN - 1) ? p + 1 : p);
#pragma unroll
                for (int j = 0; j < 4; ++j)
                    bn[j] = Bfr[(size_t)((jt0 + j) * 32 + pn * 4 + kc2) * 64 + lane];
            }
#pragma unroll
            for (int i = 0; i < 8; ++i)
#pragma unroll
                for (int j = 0; j < 4; ++j)
                    acc[i][j] = __builtin_amdgcn_mfma_f32_16x16x32_bf16(
                        af[i], bf[j], acc[i][j], 0, 0, 0);
#pragma unroll
            for (int j = 0; j < 4; ++j) bf[j] = bn[j];
        }

        if (p < PHN - 1) {
#pragma unroll
            for (int q = 0; q < 8; ++q) {
                int row  = wave * 16 + q * 2 + s_rsub;
                int slot = s_c16 ^ (row & 7);
                uint2 u = {pack2(ld[q].x, ld[q].y), pack2(ld[q].z, ld[q].w)};
                *(uint2*)(&slab[(p + 1) & 1][row * 128 + slot * 8 + s_b8 * 4]) = u;
            }
        }
    }

    // epilogue: rowsum over this wave's 64 cols, tanh(e + c) * v
    float rowsum[8][4];
#pragma unroll
    for (int i = 0; i < 8; ++i)
#pragma unroll
        for (int r = 0; r < 4; ++r) rowsum[i][r] = 0.f;

#pragma unroll
    for (int j = 0; j < 4; ++j) {
        const int n  = cb + j * 16 + lc;
        const float vn = v[n];
        const float cv = c[b * HDIM + n];
#pragma unroll
        for (int i = 0; i < 8; ++i)
#pragma unroll
            for (int r = 0; r < 4; ++r)
                rowsum[i][r] = fmaf(fast_tanh(acc[i][j][r] + cv), vn,
                                    rowsum[i][r]);
    }

    // in-block reduction across the 8 waves (disjoint 64-col slices, same
    // 128 rows). red overlays slab (no LDS reads after final barrier).
    __syncthreads();
    float* red = (float*)slab;
#pragma unroll
    for (int i = 0; i < 8; ++i)
#pragma unroll
        for (int r = 0; r < 4; ++r) {
            float x = rowsum[i][r];
            x += __shfl_xor(x, 8);
            x += __shfl_xor(x, 4);
            x += __shfl_xor(x, 2);
            x += __shfl_xor(x, 1);
            if (lc == 0) red[wave * 128 + i * 16 + grp * 4 + r] = x;
        }
    __syncthreads();
    if (tid < 128) {
        float ssum = 0.f;
#pragma unroll
        for (int w = 0; w < 8; ++w) ssum += red[w * 128 + tid];
        part[(size_t)nhalf * MTOT + m0 + tid] = ssum;
    }
}

// ---- softmax over S=2048 per batch, summing 2 partial col-half slices ----
__global__ __launch_bounds__(256) void softmax_k(const float* __restrict__ part,
                                                 float* __restrict__ out) {
    __shared__ float wred[4];
    const int bb = blockIdx.x;
    const int tid = threadIdx.x;
    const int wave = tid >> 6, lane = tid & 63;

    float vals[8];
    float lmax = -INFINITY;
#pragma unroll
    for (int q = 0; q < 8; ++q) {
        const size_t idx = (size_t)bb * SDIM + q * 256 + tid;
        vals[q] = part[idx] + part[(size_t)MTOT + idx];
        lmax = fmaxf(lmax, vals[q]);
    }
    for (int off = 32; off; off >>= 1) lmax = fmaxf(lmax, __shfl_xor(lmax, off));
    if (lane == 0) wred[wave] = lmax;
    __syncthreads();
    lmax = fmaxf(fmaxf(wred[0], wred[1]), fmaxf(wred[2], wred[3]));
    __syncthreads();

    float e[8];
    float s = 0.f;
#pragma unroll
    for (int q = 0; q < 8; ++q) {
        e[q] = __expf(vals[q] - lmax);
        s += e[q];
    }
    for (int off = 32; off; off >>= 1) s += __shfl_xor(s, off);
    if (lane == 0) wred[wave] = s;
    __syncthreads();
    s = wred[0] + wred[1] + wred[2] + wred[3];
    const float inv = 1.f / s;
#pragma unroll
    for (int q = 0; q < 8; ++q)
        out[(size_t)bb * SDIM + q * 256 + tid] = e[q] * inv;
}

extern "C" void kernel_launch(void* const* d_in, const int* in_sizes, int n_in,
                              void* d_out, int out_size, void* d_ws, size_t ws_size,
                              hipStream_t stream) {
    const float* hidden = (const float*)d_in[0];   // (1, 32, 1024)
    const float* enc    = (const float*)d_in[1];   // (32, 2048, 1024)
    const float* W      = (const float*)d_in[2];   // (1024, 2048)
    const float* battn  = (const float*)d_in[3];   // (1024,)
    const float* v      = (const float*)d_in[4];   // (1024,)
    float* out = (float*)d_out;                    // (32, 2048)

    char* ws = (char*)d_ws;
    float* c             = (float*)ws;                           // 128 KB
    float* part          = (float*)(ws + (128 << 10));           // 512 KB
    unsigned short* Wbf2 = (unsigned short*)(ws + (640 << 10));  // 2 MB

    hipLaunchKernelGGL(prep,       dim3(1536), dim3(256), 0, stream, W, Wbf2, hidden, battn, c);
    hipLaunchKernelGGL(attn_fused, dim3(1024), dim3(512), 0, stream, enc, Wbf2, c, v, part);
    hipLaunchKernelGGL(softmax_k,  dim3(32),   dim3(256), 0, stream, part, out);
}